// Round 22
// baseline (131.294 us; speedup 1.0000x reference)
//
#include <hip/hip_runtime.h>
#include <hip/hip_bf16.h>
#include <hip/hip_fp8.h>

// ---------------------------------------------------------------------------
// GraphSAGE 2-layer forward.
//   h   = relu( mean_agg(x) @ W1_l + b1 + x @ W1_r )
//   out =       mean_agg(h) @ W2_l + b2 + h @ W2_r
// agg(x)@W == agg(x@W): transform-then-aggregate. Biases folded into GEMM
// epilogues. MFMA GEMMs with swapped operands. p,g fp8 e4m3 gather buffers
// (one cache line per row); q,r,h bf16; out fp32. csr ushort.
// CSR build, ZERO global atomics, NRANGE=8 x NSTRIPE=64:
//   D1a partition+wt: 64 stripe-blocks read edges ONCE, ballot-append each
//       edge to bucket (range, stripe). (r22: replaces the 8x re-stream that
//       the old fused hist did.) Weight transpose backfills.
//   D1b hist: block (r,j) LDS-histograms ONLY its bucket.
//   D2 scan16 / D3 add_off_base: row_start + absolute cursors.
//   D4 gemm1(reg-weights)+scatter fused.
//   D5 agg1(fp8) + fused GEMM-2 (g fp8, r bf16).  D6 agg2 (fp8 g).
// ---------------------------------------------------------------------------

typedef __attribute__((ext_vector_type(8))) short bf16x8;
typedef __attribute__((ext_vector_type(4))) float f32x4;
typedef __attribute__((ext_vector_type(2))) float f32x2;

static __device__ __forceinline__ float bf_lo(unsigned u) {
    u <<= 16; return __builtin_bit_cast(float, u);
}
static __device__ __forceinline__ float bf_hi(unsigned u) {
    u &= 0xffff0000u; return __builtin_bit_cast(float, u);
}
static __device__ __forceinline__ unsigned short f2bf(float f) {
    __hip_bfloat16 b = __float2bfloat16(f);
    return __builtin_bit_cast(unsigned short, b);
}
static __device__ __forceinline__ unsigned packbf(float lo, float hi) {
    return (unsigned)f2bf(lo) | ((unsigned)f2bf(hi) << 16);
}

// ---- fp8 e4m3 encode/decode (HW converts on gfx950) ----
#if __has_builtin(__builtin_amdgcn_cvt_pk_fp8_f32) && __has_builtin(__builtin_amdgcn_cvt_pk_f32_fp8)
static __device__ __forceinline__ unsigned pk4_fp8(float a, float b, float c, float d) {
    int o = 0;
    o = __builtin_amdgcn_cvt_pk_fp8_f32(a, b, o, false);
    o = __builtin_amdgcn_cvt_pk_fp8_f32(c, d, o, true);
    return (unsigned)o;
}
static __device__ __forceinline__ void acc8_fp8(float* acc, uint2 v) {
    f32x2 a = __builtin_amdgcn_cvt_pk_f32_fp8((int)v.x, false);
    f32x2 b = __builtin_amdgcn_cvt_pk_f32_fp8((int)v.x, true);
    f32x2 c = __builtin_amdgcn_cvt_pk_f32_fp8((int)v.y, false);
    f32x2 d = __builtin_amdgcn_cvt_pk_f32_fp8((int)v.y, true);
    acc[0] += a[0]; acc[1] += a[1]; acc[2] += b[0]; acc[3] += b[1];
    acc[4] += c[0]; acc[5] += c[1]; acc[6] += d[0]; acc[7] += d[1];
}
static __device__ __forceinline__ void acc4_fp8(float* acc, unsigned v) {
    f32x2 a = __builtin_amdgcn_cvt_pk_f32_fp8((int)v, false);
    f32x2 b = __builtin_amdgcn_cvt_pk_f32_fp8((int)v, true);
    acc[0] += a[0]; acc[1] += a[1]; acc[2] += b[0]; acc[3] += b[1];
}
#else
static __device__ __forceinline__ unsigned pk4_fp8(float a, float b, float c, float d) {
    __hip_fp8_e4m3 ea(a), eb(b), ec(c), ed(d);
    return (unsigned)ea.__x | ((unsigned)eb.__x << 8) |
           ((unsigned)ec.__x << 16) | ((unsigned)ed.__x << 24);
}
static __device__ __forceinline__ float f8dec_sw(unsigned v, int s) {
    __hip_fp8_e4m3 t; t.__x = (unsigned char)(v >> (s * 8)); return (float)t;
}
static __device__ __forceinline__ void acc8_fp8(float* acc, uint2 v) {
    acc[0] += f8dec_sw(v.x, 0); acc[1] += f8dec_sw(v.x, 1);
    acc[2] += f8dec_sw(v.x, 2); acc[3] += f8dec_sw(v.x, 3);
    acc[4] += f8dec_sw(v.y, 0); acc[5] += f8dec_sw(v.y, 1);
    acc[6] += f8dec_sw(v.y, 2); acc[7] += f8dec_sw(v.y, 3);
}
static __device__ __forceinline__ void acc4_fp8(float* acc, unsigned v) {
    acc[0] += f8dec_sw(v, 0); acc[1] += f8dec_sw(v, 1);
    acc[2] += f8dec_sw(v, 2); acc[3] += f8dec_sw(v, 3);
}
#endif

#define NRANGE     8
#define RANGE_W    6250     // N == 8*6250 exactly
#define PACKED_W   3125     // RANGE_W/2, two ushort counts per int
#define NSTRIPE    64
#define NHIST      (NRANGE * NSTRIPE)   // 512
#define BUCKET_CAP 12512    // >= max stripe length (12500)

static __device__ __forceinline__ int stripe_len(int E) {
    return ((E / NSTRIPE) + 3) & ~3;
}

// ---------------- D1a: partition (edges read ONCE) + weight prep ----------

__global__ __launch_bounds__(512) void part_wt_kernel(
    const int* __restrict__ src, const int* __restrict__ dst,
    unsigned* __restrict__ bucket, int* __restrict__ bucket_cnt, int E, int N,
    const float* __restrict__ W1l, const float* __restrict__ W1r,
    const float* __restrict__ W2l, const float* __restrict__ W2r,
    unsigned short* __restrict__ T1l, unsigned short* __restrict__ T1r,
    unsigned short* __restrict__ T2l, unsigned short* __restrict__ T2r) {
    __shared__ int lcnt[NRANGE];
    const int tid = threadIdx.x;
    if ((int)blockIdx.x >= NSTRIPE) {
        int i = (blockIdx.x - NSTRIPE) * 512 + tid;
        if (i < 16384) {
            int k = i >> 7, n = i & 127;
            T1l[n * 128 + k] = f2bf(W1l[i]);
            T1r[n * 128 + k] = f2bf(W1r[i]);
        } else if (i < 16384 + 8192) {
            int m = i - 16384;
            int k = m >> 6, n = m & 63;
            T2l[n * 128 + k] = f2bf(W2l[m]);
            T2r[n * 128 + k] = f2bf(W2r[m]);
        }
        return;
    }
    const int j = blockIdx.x;
    if (tid < NRANGE) lcnt[tid] = 0;
    __syncthreads();
    const int wl = tid & 63;
    const int stripe = stripe_len(E);
    const int s0 = j * stripe;
    const int s1 = min(E, s0 + stripe);

    auto commit = [&](int d, int s) {
        int rr = d / RANGE_W;          // 0..7
#pragma unroll
        for (int r = 0; r < NRANGE; ++r) {
            bool pred = (rr == r);
            unsigned long long m = __ballot(pred);
            if (m) {
                int cnt = __popcll(m);
                int ldr = (int)__builtin_ctzll(m);
                int base = 0;
                if (wl == ldr) base = atomicAdd(&lcnt[r], cnt);
                base = __shfl(base, ldr, 64);
                if (pred) {
                    int pre = __popcll(m & ((1ull << wl) - 1ull));
                    bucket[(size_t)(r * NSTRIPE + j) * BUCKET_CAP + base + pre] =
                        ((unsigned)s << 16) | (unsigned)d;
                }
            }
        }
    };

    for (int e = s0 + tid * 4; e < s1; e += 2048) {
        int4 d4 = *(const int4*)(dst + e);
        int4 s4 = *(const int4*)(src + e);
        commit(d4.x, s4.x);
        commit(d4.y, s4.y);
        commit(d4.z, s4.z);
        commit(d4.w, s4.w);
    }
    __syncthreads();
    if (tid < NRANGE) bucket_cnt[tid * NSTRIPE + j] = lcnt[tid];
}

// ---------------- D1b: histogram from buckets ----------------

__global__ __launch_bounds__(256) void hist_kernel(
    const unsigned* __restrict__ bucket, const int* __restrict__ bucket_cnt,
    int* __restrict__ hist, int N) {
    __shared__ int lhist[PACKED_W];
    const int tid = threadIdx.x;
    const int b = blockIdx.x;
    const int r = b & (NRANGE - 1);
    const int j = b >> 3;
    const int lo = r * RANGE_W;
    for (int i = tid; i < PACKED_W; i += 256) lhist[i] = 0;
    __syncthreads();
    const int cnt = bucket_cnt[r * NSTRIPE + j];
    const unsigned* gbk = bucket + (size_t)(r * NSTRIPE + j) * BUCKET_CAP;
    for (int i = tid; i < cnt; i += 256) {
        int a = (int)(gbk[i] & 0xffffu) - lo;   // in range by construction
        atomicAdd(&lhist[a >> 1], 1u << ((a & 1) * 16));
    }
    __syncthreads();
    int* gh = hist + ((size_t)r * NSTRIPE + j) * PACKED_W;
    for (int i = tid; i < PACKED_W; i += 256) gh[i] = lhist[i];
}

// ---------------- D2: scan ----------------

__global__ __launch_bounds__(256) void scan16_kernel(const int* __restrict__ hist,
                                                     int* __restrict__ row_start,
                                                     int* __restrict__ bsum, int N) {
    __shared__ int lds[256];
    int i = blockIdx.x * 256 + threadIdx.x;
    int v = 0;
    if (i < N) {
        int r = i / RANGE_W, loc = i - r * RANGE_W;
        const int* hp = hist + (size_t)r * NSTRIPE * PACKED_W + (loc >> 1);
        int sh = (loc & 1) * 16;
#pragma unroll 8
        for (int j = 0; j < NSTRIPE; ++j) v += (hp[j * PACKED_W] >> sh) & 0xffff;
    }
    lds[threadIdx.x] = v;
    __syncthreads();
    for (int off = 1; off < 256; off <<= 1) {
        int t = (threadIdx.x >= off) ? lds[threadIdx.x - off] : 0;
        __syncthreads();
        lds[threadIdx.x] += t;
        __syncthreads();
    }
    if (i < N) row_start[i] = lds[threadIdx.x] - v;
    if (threadIdx.x == 255) bsum[blockIdx.x] = lds[255];
}

// ---------------- D3: global prefix + absolute cursors ----------------

__global__ __launch_bounds__(256) void add_off_base_kernel(int* __restrict__ row_start,
                                                           const int* __restrict__ bsum,
                                                           const int* __restrict__ hist,
                                                           int* __restrict__ cur,
                                                           int N, int E) {
    __shared__ int lds[256];
    int b = blockIdx.x;
    lds[threadIdx.x] = (threadIdx.x < b) ? bsum[threadIdx.x] : 0;
    __syncthreads();
    for (int off = 128; off > 0; off >>= 1) {
        if (threadIdx.x < off) lds[threadIdx.x] += lds[threadIdx.x + off];
        __syncthreads();
    }
    int prefix = lds[0];
    int i = b * 256 + threadIdx.x;
    if (i < N) {
        int s = row_start[i] + prefix;
        row_start[i] = s;
        int r = i / RANGE_W, loc = i - r * RANGE_W;
        const int* hp = hist + (size_t)r * NSTRIPE * PACKED_W + (loc >> 1);
        int* cp = cur + (size_t)r * NSTRIPE * RANGE_W + loc;
        int sh = (loc & 1) * 16;
#pragma unroll 8
        for (int j = 0; j < NSTRIPE; ++j) {
            int h = (hp[j * PACKED_W] >> sh) & 0xffff;
            cp[j * RANGE_W] = s;
            s += h;
        }
    }
    if (b == 0 && threadIdx.x == 0) row_start[N] = E;
}

// ---------------- D4: GEMM-1 (weights in registers) + scatter (fused) ------

__global__ __launch_bounds__(256) void gemm1_scatter_kernel(
    const float* __restrict__ Av,
    const unsigned short* __restrict__ WTl,
    const unsigned short* __restrict__ WTr,
    const float* __restrict__ bias,
    unsigned char* __restrict__ Pl,
    unsigned short* __restrict__ Qr, int M,
    const unsigned* __restrict__ bucket,
    const int* __restrict__ bucket_cnt,
    const int* __restrict__ cur, unsigned short* __restrict__ csr_src,
    int nGemmWg, int N) {
    __shared__ __align__(16) int lcur[RANGE_W];
    const int tid = threadIdx.x;

    if ((int)blockIdx.x < nGemmWg) {
        const int wave = tid >> 6;
        const int lane = tid & 63;
        const int lr = lane & 15;
        const int lk = lane >> 4;

        bf16x8 bfr[2][2][4];
        float4 b4[2];
#pragma unroll
        for (int c = 0; c < 2; ++c) {
            int ct = wave * 2 + c;
            const unsigned short* Bl = WTl + (size_t)(ct * 16 + lr) * 128 + lk * 8;
            const unsigned short* Br = WTr + (size_t)(ct * 16 + lr) * 128 + lk * 8;
#pragma unroll
            for (int s = 0; s < 4; ++s) {
                bfr[c][0][s] = *(const bf16x8*)(Bl + s * 32);
                bfr[c][1][s] = *(const bf16x8*)(Br + s * 32);
            }
            b4[c] = *(const float4*)(bias + ct * 16 + lk * 4);
        }

#pragma unroll
        for (int rt = 0; rt < 4; ++rt) {
            const int m0 = blockIdx.x * 64 + rt * 16;
            int arow = m0 + lr;
            if (arow >= M) arow = M - 1;
            const bool rowok = (m0 + lr) < M;

            bf16x8 xf[4];
            const float* Ab = Av + (size_t)arow * 128 + lk * 8;
#pragma unroll
            for (int s = 0; s < 4; ++s) {
                float4 v0 = *(const float4*)(Ab + s * 32);
                float4 v1 = *(const float4*)(Ab + s * 32 + 4);
                unsigned short t[8] = {f2bf(v0.x), f2bf(v0.y), f2bf(v0.z), f2bf(v0.w),
                                       f2bf(v1.x), f2bf(v1.y), f2bf(v1.z), f2bf(v1.w)};
                xf[s] = *(const bf16x8*)t;
            }

#pragma unroll
            for (int c = 0; c < 2; ++c) {
                int ct = wave * 2 + c;
                f32x4 accL = {0.f, 0.f, 0.f, 0.f};
                f32x4 accR = {0.f, 0.f, 0.f, 0.f};
#pragma unroll
                for (int s = 0; s < 4; ++s) {
                    accL = __builtin_amdgcn_mfma_f32_16x16x32_bf16(bfr[c][0][s], xf[s], accL, 0, 0, 0);
                    accR = __builtin_amdgcn_mfma_f32_16x16x32_bf16(bfr[c][1][s], xf[s], accR, 0, 0, 0);
                }
                if (rowok) {
                    unsigned pk = pk4_fp8(accL[0], accL[1], accL[2], accL[3]);
                    ushort4 oR;
                    oR.x = f2bf(accR[0] + b4[c].x); oR.y = f2bf(accR[1] + b4[c].y);
                    oR.z = f2bf(accR[2] + b4[c].z); oR.w = f2bf(accR[3] + b4[c].w);
                    size_t base = (size_t)(m0 + lr) * 128 + ct * 16 + lk * 4;
                    *(unsigned*)(Pl + base) = pk;
                    *(ushort4*)(Qr + base) = oR;
                }
            }
        }
        return;
    }

    // ---- scatter path ----
    const int b = blockIdx.x - nGemmWg;
    const int r = b & (NRANGE - 1);
    const int j = b >> 3;
    const int lo = r * RANGE_W;
    const int w = min(N - lo, RANGE_W);
    const int* gb = cur + ((size_t)r * NSTRIPE + j) * RANGE_W;
    {
        int w4 = w & ~3;
        for (int i = tid * 4; i < w4; i += 1024)
            *(int4*)(&lcur[i]) = *(const int4*)(gb + i);
        for (int i = w4 + tid; i < w; i += 256) lcur[i] = gb[i];
    }
    __syncthreads();
    const int cnt = bucket_cnt[r * NSTRIPE + j];
    const unsigned* gbk = bucket + (size_t)(r * NSTRIPE + j) * BUCKET_CAP;
    for (int i = tid; i < cnt; i += 256) {
        unsigned pk = gbk[i];
        int node = (int)(pk & 0xffffu) - lo;
        int pos = atomicAdd(&lcur[node], 1);
        csr_src[pos] = (unsigned short)(pk >> 16);
    }
}

// ---------------- D5: agg1 + fused GEMM-2 (g fp8, r bf16) ----------------

__global__ __launch_bounds__(256) void agg1_gemm2_kernel(
    const unsigned char* __restrict__ p,
    const unsigned short* __restrict__ q,
    const int* __restrict__ row_start,
    const unsigned short* __restrict__ csr_src,
    const unsigned short* __restrict__ wt2l,
    const unsigned short* __restrict__ wt2r,
    const float* __restrict__ b2,
    unsigned char* __restrict__ g,
    unsigned short* __restrict__ rbuf, int N) {
    __shared__ unsigned short hsh[16][136];
    int tid = threadIdx.x;
    int nl = tid >> 4;
    int lane = tid & 15;
    int n = blockIdx.x * 16 + nl;
    int na = min(n, N - 1);
    int s0 = row_start[na], s1 = row_start[na + 1];
    float acc[8] = {};
    const unsigned char* pc = p + lane * 8;
    int e = s0;
    for (; e + 7 < s1; e += 8) {
        uint2 v0 = *(const uint2*)(pc + (size_t)csr_src[e]     * 128);
        uint2 v1 = *(const uint2*)(pc + (size_t)csr_src[e + 1] * 128);
        uint2 v2 = *(const uint2*)(pc + (size_t)csr_src[e + 2] * 128);
        uint2 v3 = *(const uint2*)(pc + (size_t)csr_src[e + 3] * 128);
        uint2 v4 = *(const uint2*)(pc + (size_t)csr_src[e + 4] * 128);
        uint2 v5 = *(const uint2*)(pc + (size_t)csr_src[e + 5] * 128);
        uint2 v6 = *(const uint2*)(pc + (size_t)csr_src[e + 6] * 128);
        uint2 v7 = *(const uint2*)(pc + (size_t)csr_src[e + 7] * 128);
        acc8_fp8(acc, v0); acc8_fp8(acc, v1); acc8_fp8(acc, v2); acc8_fp8(acc, v3);
        acc8_fp8(acc, v4); acc8_fp8(acc, v5); acc8_fp8(acc, v6); acc8_fp8(acc, v7);
    }
    for (; e + 3 < s1; e += 4) {
        uint2 v0 = *(const uint2*)(pc + (size_t)csr_src[e]     * 128);
        uint2 v1 = *(const uint2*)(pc + (size_t)csr_src[e + 1] * 128);
        uint2 v2 = *(const uint2*)(pc + (size_t)csr_src[e + 2] * 128);
        uint2 v3 = *(const uint2*)(pc + (size_t)csr_src[e + 3] * 128);
        acc8_fp8(acc, v0); acc8_fp8(acc, v1); acc8_fp8(acc, v2); acc8_fp8(acc, v3);
    }
    for (; e < s1; ++e) {
        uint2 v0 = *(const uint2*)(pc + (size_t)csr_src[e] * 128);
        acc8_fp8(acc, v0);
    }
    float inv = 1.0f / (float)max(s1 - s0, 1);
    uint4 qv = *(const uint4*)(q + (size_t)na * 128 + lane * 8);
    float hv[8];
    hv[0] = fmaxf(fmaf(acc[0], inv, bf_lo(qv.x)), 0.f);
    hv[1] = fmaxf(fmaf(acc[1], inv, bf_hi(qv.x)), 0.f);
    hv[2] = fmaxf(fmaf(acc[2], inv, bf_lo(qv.y)), 0.f);
    hv[3] = fmaxf(fmaf(acc[3], inv, bf_hi(qv.y)), 0.f);
    hv[4] = fmaxf(fmaf(acc[4], inv, bf_lo(qv.z)), 0.f);
    hv[5] = fmaxf(fmaf(acc[5], inv, bf_hi(qv.z)), 0.f);
    hv[6] = fmaxf(fmaf(acc[6], inv, bf_lo(qv.w)), 0.f);
    hv[7] = fmaxf(fmaf(acc[7], inv, bf_hi(qv.w)), 0.f);
    uint4 o;
    o.x = packbf(hv[0], hv[1]); o.y = packbf(hv[2], hv[3]);
    o.z = packbf(hv[4], hv[5]); o.w = packbf(hv[6], hv[7]);
    *(uint4*)(&hsh[nl][lane * 8]) = o;
    __syncthreads();

    const int wave = tid >> 6;
    const int wl = tid & 63;
    const int lr = wl & 15;
    const int lk = wl >> 4;
    const int gn = blockIdx.x * 16 + lr;
    const bool rowok = gn < N;
    const int ct = wave;
    f32x4 aL = {0.f, 0.f, 0.f, 0.f};
    f32x4 aR = {0.f, 0.f, 0.f, 0.f};
#pragma unroll
    for (int s = 0; s < 4; ++s) {
        bf16x8 hvv = *(const bf16x8*)(&hsh[lr][lk * 8 + s * 32]);
        bf16x8 bl = *(const bf16x8*)(wt2l + (size_t)(ct * 16 + lr) * 128 + lk * 8 + s * 32);
        bf16x8 br = *(const bf16x8*)(wt2r + (size_t)(ct * 16 + lr) * 128 + lk * 8 + s * 32);
        aL = __builtin_amdgcn_mfma_f32_16x16x32_bf16(bl, hvv, aL, 0, 0, 0);
        aR = __builtin_amdgcn_mfma_f32_16x16x32_bf16(br, hvv, aR, 0, 0, 0);
    }
    if (rowok) {
        float4 b4 = *(const float4*)(b2 + ct * 16 + lk * 4);
        unsigned pg = pk4_fp8(aL[0], aL[1], aL[2], aL[3]);
        ushort4 oR;
        oR.x = f2bf(aR[0] + b4.x); oR.y = f2bf(aR[1] + b4.y);
        oR.z = f2bf(aR[2] + b4.z); oR.w = f2bf(aR[3] + b4.w);
        size_t base = (size_t)gn * 64 + ct * 16 + lk * 4;
        *(unsigned*)(g + base) = pg;
        *(ushort4*)(rbuf + base) = oR;
    }
}

// ---------------- D6: agg2 (fp8 g gather) ----------------

__global__ __launch_bounds__(256) void agg2_kernel(const unsigned char* __restrict__ g,
                                                   const unsigned short* __restrict__ r,
                                                   const int* __restrict__ row_start,
                                                   const unsigned short* __restrict__ csr_src,
                                                   float* __restrict__ out, int N) {
    int tid = threadIdx.x;
    int n = blockIdx.x * 16 + (tid >> 4);
    int lane = tid & 15;
    if (n >= N) return;
    int s0 = row_start[n], s1 = row_start[n + 1];
    float acc[4] = {};
    const unsigned char* gc = g + lane * 4;
    int e = s0;
    for (; e + 7 < s1; e += 8) {
        unsigned v0 = *(const unsigned*)(gc + (size_t)csr_src[e]     * 64);
        unsigned v1 = *(const unsigned*)(gc + (size_t)csr_src[e + 1] * 64);
        unsigned v2 = *(const unsigned*)(gc + (size_t)csr_src[e + 2] * 64);
        unsigned v3 = *(const unsigned*)(gc + (size_t)csr_src[e + 3] * 64);
        unsigned v4 = *(const unsigned*)(gc + (size_t)csr_src[e + 4] * 64);
        unsigned v5 = *(const unsigned*)(gc + (size_t)csr_src[e + 5] * 64);
        unsigned v6 = *(const unsigned*)(gc + (size_t)csr_src[e + 6] * 64);
        unsigned v7 = *(const unsigned*)(gc + (size_t)csr_src[e + 7] * 64);
        acc4_fp8(acc, v0); acc4_fp8(acc, v1); acc4_fp8(acc, v2); acc4_fp8(acc, v3);
        acc4_fp8(acc, v4); acc4_fp8(acc, v5); acc4_fp8(acc, v6); acc4_fp8(acc, v7);
    }
    for (; e + 3 < s1; e += 4) {
        unsigned v0 = *(const unsigned*)(gc + (size_t)csr_src[e]     * 64);
        unsigned v1 = *(const unsigned*)(gc + (size_t)csr_src[e + 1] * 64);
        unsigned v2 = *(const unsigned*)(gc + (size_t)csr_src[e + 2] * 64);
        unsigned v3 = *(const unsigned*)(gc + (size_t)csr_src[e + 3] * 64);
        acc4_fp8(acc, v0); acc4_fp8(acc, v1); acc4_fp8(acc, v2); acc4_fp8(acc, v3);
    }
    for (; e < s1; ++e) {
        unsigned v0 = *(const unsigned*)(gc + (size_t)csr_src[e] * 64);
        acc4_fp8(acc, v0);
    }
    float inv = 1.0f / (float)max(s1 - s0, 1);
    uint2 rv = *(const uint2*)(r + (size_t)n * 64 + lane * 4);
    float4 o;
    o.x = fmaf(acc[0], inv, bf_lo(rv.x));
    o.y = fmaf(acc[1], inv, bf_hi(rv.x));
    o.z = fmaf(acc[2], inv, bf_lo(rv.y));
    o.w = fmaf(acc[3], inv, bf_hi(rv.y));
    *(float4*)(out + (size_t)n * 64 + lane * 4) = o;
}

// ---------------------------------------------------------------------------

extern "C" void kernel_launch(void* const* d_in, const int* in_sizes, int n_in,
                              void* d_out, int out_size, void* d_ws, size_t ws_size,
                              hipStream_t stream) {
    const float* x    = (const float*)d_in[0];
    const int*   ei   = (const int*)d_in[1];
    const float* W1_l = (const float*)d_in[2];
    const float* b1   = (const float*)d_in[3];
    const float* W1_r = (const float*)d_in[4];
    const float* W2_l = (const float*)d_in[5];
    const float* b2   = (const float*)d_in[6];
    const float* W2_r = (const float*)d_in[7];

    const int N = in_sizes[0] / 128;   // 50000
    const int E = in_sizes[1] / 2;     // 800000
    const int* e_src = ei;
    const int* e_dst = ei + E;

    // ---- workspace layout ----
    char* ws = (char*)d_ws;
    auto align256 = [](size_t v) { return (v + 255) & ~(size_t)255; };
    size_t off = 0;
    int* row_start = (int*)(ws + off); off += align256((size_t)(N + 1) * 4);
    int* bsum      = (int*)(ws + off); off += align256(1024);
    int* hist      = (int*)(ws + off); off += align256((size_t)NRANGE * NSTRIPE * PACKED_W * 4);
    int* cur       = (int*)(ws + off); off += align256((size_t)NRANGE * NSTRIPE * RANGE_W * 4);
    unsigned* bucket = (unsigned*)(ws + off); off += align256((size_t)NHIST * BUCKET_CAP * 4);
    int* bucket_cnt  = (int*)(ws + off); off += align256((size_t)NHIST * 4);
    unsigned short* csr_src = (unsigned short*)(ws + off); off += align256((size_t)E * 2);
    unsigned char* p_f8   = (unsigned char*)(ws + off);  off += align256((size_t)N * 128);
    unsigned short* qr_bf = (unsigned short*)(ws + off); off += align256((size_t)N * 128 * 2);
    unsigned char* g_f8   = (unsigned char*)(ws + off);  off += align256((size_t)N * 64);
    unsigned short* r_bf  = (unsigned short*)(ws + off); off += align256((size_t)N * 64 * 2);
    unsigned short* wt1l  = (unsigned short*)(ws + off); off += align256(128 * 128 * 2);
    unsigned short* wt1r  = (unsigned short*)(ws + off); off += align256(128 * 128 * 2);
    unsigned short* wt2l  = (unsigned short*)(ws + off); off += align256(128 * 64 * 2);
    unsigned short* wt2r  = (unsigned short*)(ws + off); off += align256(128 * 64 * 2);
    float* out = (float*)d_out;

    const int nb = (N + 255) / 256;
    const int nGemm1Wg = (N + 63) / 64;                   // 782 (64 rows/block)
    const int nWtWg = (16384 + 8192 + 511) / 512;         // 48

    // ---- D1a: partition (edges once) + weight prep ----
    part_wt_kernel<<<NSTRIPE + nWtWg, 512, 0, stream>>>(
        e_src, e_dst, bucket, bucket_cnt, E, N,
        W1_l, W1_r, W2_l, W2_r, wt1l, wt1r, wt2l, wt2r);
    // ---- D1b: histogram from buckets ----
    hist_kernel<<<NHIST, 256, 0, stream>>>(bucket, bucket_cnt, hist, N);
    // ---- D2/D3: CSR scan (no global atomics) ----
    scan16_kernel<<<nb, 256, 0, stream>>>(hist, row_start, bsum, N);
    add_off_base_kernel<<<nb, 256, 0, stream>>>(row_start, bsum, hist, cur, N, E);
    // ---- D4: GEMM-1 (reg weights) + scatter, fused (gemm first) ----
    gemm1_scatter_kernel<<<nGemm1Wg + NHIST, 256, 0, stream>>>(
        x, wt1l, wt1r, b1, p_f8, qr_bf, N,
        bucket, bucket_cnt, cur, csr_src, nGemm1Wg, N);
    // ---- D5: agg1 (fp8 gather) + fused GEMM-2 (g fp8, r bf16) ----
    agg1_gemm2_kernel<<<(N + 15) / 16, 256, 0, stream>>>(
        p_f8, qr_bf, row_start, csr_src, wt2l, wt2r, b2, g_f8, r_bf, N);
    // ---- D6: agg2 (fp8 g) ----
    agg2_kernel<<<(N + 15) / 16, 256, 0, stream>>>(g_f8, r_bf, row_start,
                                                   csr_src, out, N);
}

// Round 23
// 103.033 us; speedup vs baseline: 1.2743x; 1.2743x over previous
//
#include <hip/hip_runtime.h>
#include <hip/hip_bf16.h>
#include <hip/hip_fp8.h>

// ---------------------------------------------------------------------------
// GraphSAGE 2-layer forward.  (r23: revert to the r21 config, 103.2us —
// r22's partition split regressed to 131us: 64 blocks + 8 serialized
// ballots/element lost to the old 512-block single-ballot fused hist.)
//   h   = relu( mean_agg(x) @ W1_l + b1 + x @ W1_r )
//   out =       mean_agg(h) @ W2_l + b2 + h @ W2_r
// agg(x)@W == agg(x@W): transform-then-aggregate. Biases folded into GEMM
// epilogues. MFMA GEMMs with swapped operands (lane holds 4 consecutive
// output channels). Gather buffers p AND g in fp8 e4m3 (one cache line per
// gathered row); q,r,h bf16; out fp32. csr ushort.
// CSR build, ZERO global atomics, NRANGE=8 x NSTRIPE=64:
//   D1 hist+bucket+wt   |  D2 scan16  |  D3 add_off_base
//   D4 gemm1+scatter FUSED: gemm blocks first (weights in VGPRs, r20 fix),
//      scatter blocks backfill (bucket -> LDS-cursor -> csr).
//   D5 agg1(fp8 gather) + fused GEMM-2 (g fp8, r bf16)  |  D6 agg2 (fp8 g).
// ---------------------------------------------------------------------------

typedef __attribute__((ext_vector_type(8))) short bf16x8;
typedef __attribute__((ext_vector_type(4))) float f32x4;
typedef __attribute__((ext_vector_type(2))) float f32x2;

static __device__ __forceinline__ float bf_lo(unsigned u) {
    u <<= 16; return __builtin_bit_cast(float, u);
}
static __device__ __forceinline__ float bf_hi(unsigned u) {
    u &= 0xffff0000u; return __builtin_bit_cast(float, u);
}
static __device__ __forceinline__ unsigned short f2bf(float f) {
    __hip_bfloat16 b = __float2bfloat16(f);
    return __builtin_bit_cast(unsigned short, b);
}
static __device__ __forceinline__ unsigned packbf(float lo, float hi) {
    return (unsigned)f2bf(lo) | ((unsigned)f2bf(hi) << 16);
}

// ---- fp8 e4m3 encode/decode (HW converts on gfx950) ----
#if __has_builtin(__builtin_amdgcn_cvt_pk_fp8_f32) && __has_builtin(__builtin_amdgcn_cvt_pk_f32_fp8)
static __device__ __forceinline__ unsigned pk4_fp8(float a, float b, float c, float d) {
    int o = 0;
    o = __builtin_amdgcn_cvt_pk_fp8_f32(a, b, o, false);
    o = __builtin_amdgcn_cvt_pk_fp8_f32(c, d, o, true);
    return (unsigned)o;
}
static __device__ __forceinline__ void acc8_fp8(float* acc, uint2 v) {
    f32x2 a = __builtin_amdgcn_cvt_pk_f32_fp8((int)v.x, false);
    f32x2 b = __builtin_amdgcn_cvt_pk_f32_fp8((int)v.x, true);
    f32x2 c = __builtin_amdgcn_cvt_pk_f32_fp8((int)v.y, false);
    f32x2 d = __builtin_amdgcn_cvt_pk_f32_fp8((int)v.y, true);
    acc[0] += a[0]; acc[1] += a[1]; acc[2] += b[0]; acc[3] += b[1];
    acc[4] += c[0]; acc[5] += c[1]; acc[6] += d[0]; acc[7] += d[1];
}
static __device__ __forceinline__ void acc4_fp8(float* acc, unsigned v) {
    f32x2 a = __builtin_amdgcn_cvt_pk_f32_fp8((int)v, false);
    f32x2 b = __builtin_amdgcn_cvt_pk_f32_fp8((int)v, true);
    acc[0] += a[0]; acc[1] += a[1]; acc[2] += b[0]; acc[3] += b[1];
}
#else
static __device__ __forceinline__ unsigned pk4_fp8(float a, float b, float c, float d) {
    __hip_fp8_e4m3 ea(a), eb(b), ec(c), ed(d);
    return (unsigned)ea.__x | ((unsigned)eb.__x << 8) |
           ((unsigned)ec.__x << 16) | ((unsigned)ed.__x << 24);
}
static __device__ __forceinline__ float f8dec_sw(unsigned v, int s) {
    __hip_fp8_e4m3 t; t.__x = (unsigned char)(v >> (s * 8)); return (float)t;
}
static __device__ __forceinline__ void acc8_fp8(float* acc, uint2 v) {
    acc[0] += f8dec_sw(v.x, 0); acc[1] += f8dec_sw(v.x, 1);
    acc[2] += f8dec_sw(v.x, 2); acc[3] += f8dec_sw(v.x, 3);
    acc[4] += f8dec_sw(v.y, 0); acc[5] += f8dec_sw(v.y, 1);
    acc[6] += f8dec_sw(v.y, 2); acc[7] += f8dec_sw(v.y, 3);
}
static __device__ __forceinline__ void acc4_fp8(float* acc, unsigned v) {
    acc[0] += f8dec_sw(v, 0); acc[1] += f8dec_sw(v, 1);
    acc[2] += f8dec_sw(v, 2); acc[3] += f8dec_sw(v, 3);
}
#endif

#define NRANGE     8
#define RANGE_W    6250     // N == 8*6250 exactly
#define PACKED_W   3125     // RANGE_W/2, two ushort counts per int
#define NSTRIPE    64
#define NHIST      (NRANGE * NSTRIPE)   // 512
#define BUCKET_CAP 12512    // >= max stripe length (12500)

static __device__ __forceinline__ int stripe_len(int E) {
    return ((E / NSTRIPE) + 3) & ~3;
}

// ---------------- D1: hist + bucket append + weight prep ----------------

__global__ __launch_bounds__(512) void hist_wt_kernel(
    const int* __restrict__ src, const int* __restrict__ dst,
    int* __restrict__ hist, unsigned* __restrict__ bucket,
    int* __restrict__ bucket_cnt, int E, int N,
    const float* __restrict__ W1l, const float* __restrict__ W1r,
    const float* __restrict__ W2l, const float* __restrict__ W2r,
    unsigned short* __restrict__ T1l, unsigned short* __restrict__ T1r,
    unsigned short* __restrict__ T2l, unsigned short* __restrict__ T2r) {
    __shared__ int lhist[PACKED_W];
    __shared__ int lcnt;
    const int tid = threadIdx.x;
    if ((int)blockIdx.x >= NHIST) {
        int i = (blockIdx.x - NHIST) * 512 + tid;
        if (i < 16384) {
            int k = i >> 7, n = i & 127;
            T1l[n * 128 + k] = f2bf(W1l[i]);
            T1r[n * 128 + k] = f2bf(W1r[i]);
        } else if (i < 16384 + 8192) {
            int m = i - 16384;
            int k = m >> 6, n = m & 63;
            T2l[n * 128 + k] = f2bf(W2l[m]);
            T2r[n * 128 + k] = f2bf(W2r[m]);
        }
        return;
    }
    const int b = blockIdx.x;
    const int r = b & (NRANGE - 1);
    const int j = b >> 3;
    const int lo = r * RANGE_W;
    const int w = min(N - lo, RANGE_W);
    for (int i = tid; i < PACKED_W; i += 512) lhist[i] = 0;
    if (tid == 0) lcnt = 0;
    __syncthreads();
    unsigned* gbk = bucket + (size_t)(r * NSTRIPE + j) * BUCKET_CAP;
    const int wl = tid & 63;
    const int stripe = stripe_len(E);
    const int s0 = j * stripe;
    const int s1 = min(E, s0 + stripe);

    auto commit = [&](int d, int s) {
        int a = d - lo;
        bool pred = (unsigned)a < (unsigned)w;
        if (pred) atomicAdd(&lhist[a >> 1], 1u << ((a & 1) * 16));
        unsigned long long m = __ballot(pred);
        if (m) {
            int cnt = __popcll(m);
            int ldr = (int)__builtin_ctzll(m);
            int base = 0;
            if (wl == ldr) base = atomicAdd(&lcnt, cnt);
            base = __shfl(base, ldr, 64);
            if (pred) {
                int pre = __popcll(m & ((1ull << wl) - 1ull));
                gbk[base + pre] = ((unsigned)s << 16) | (unsigned)d;
            }
        }
    };

    for (int e = s0 + tid * 4; e < s1; e += 2048) {
        int4 dA = *(const int4*)(dst + e);
        int4 sA = *(const int4*)(src + e);
        commit(dA.x, sA.x);
        commit(dA.y, sA.y);
        commit(dA.z, sA.z);
        commit(dA.w, sA.w);
    }
    __syncthreads();
    int* gh = hist + ((size_t)r * NSTRIPE + j) * PACKED_W;
    for (int i = tid; i < PACKED_W; i += 512) gh[i] = lhist[i];
    if (tid == 0) bucket_cnt[r * NSTRIPE + j] = lcnt;
}

// ---------------- D2: scan ----------------

__global__ __launch_bounds__(256) void scan16_kernel(const int* __restrict__ hist,
                                                     int* __restrict__ row_start,
                                                     int* __restrict__ bsum, int N) {
    __shared__ int lds[256];
    int i = blockIdx.x * 256 + threadIdx.x;
    int v = 0;
    if (i < N) {
        int r = i / RANGE_W, loc = i - r * RANGE_W;
        const int* hp = hist + (size_t)r * NSTRIPE * PACKED_W + (loc >> 1);
        int sh = (loc & 1) * 16;
#pragma unroll 8
        for (int j = 0; j < NSTRIPE; ++j) v += (hp[j * PACKED_W] >> sh) & 0xffff;
    }
    lds[threadIdx.x] = v;
    __syncthreads();
    for (int off = 1; off < 256; off <<= 1) {
        int t = (threadIdx.x >= off) ? lds[threadIdx.x - off] : 0;
        __syncthreads();
        lds[threadIdx.x] += t;
        __syncthreads();
    }
    if (i < N) row_start[i] = lds[threadIdx.x] - v;
    if (threadIdx.x == 255) bsum[blockIdx.x] = lds[255];
}

// ---------------- D3: global prefix + absolute cursors ----------------

__global__ __launch_bounds__(256) void add_off_base_kernel(int* __restrict__ row_start,
                                                           const int* __restrict__ bsum,
                                                           const int* __restrict__ hist,
                                                           int* __restrict__ cur,
                                                           int N, int E) {
    __shared__ int lds[256];
    int b = blockIdx.x;
    lds[threadIdx.x] = (threadIdx.x < b) ? bsum[threadIdx.x] : 0;
    __syncthreads();
    for (int off = 128; off > 0; off >>= 1) {
        if (threadIdx.x < off) lds[threadIdx.x] += lds[threadIdx.x + off];
        __syncthreads();
    }
    int prefix = lds[0];
    int i = b * 256 + threadIdx.x;
    if (i < N) {
        int s = row_start[i] + prefix;
        row_start[i] = s;
        int r = i / RANGE_W, loc = i - r * RANGE_W;
        const int* hp = hist + (size_t)r * NSTRIPE * PACKED_W + (loc >> 1);
        int* cp = cur + (size_t)r * NSTRIPE * RANGE_W + loc;
        int sh = (loc & 1) * 16;
#pragma unroll 8
        for (int j = 0; j < NSTRIPE; ++j) {
            int h = (hp[j * PACKED_W] >> sh) & 0xffff;
            cp[j * RANGE_W] = s;
            s += h;
        }
    }
    if (b == 0 && threadIdx.x == 0) row_start[N] = E;
}

// ---------------- D4: GEMM-1 (weights in registers) + scatter (fused) ------

__global__ __launch_bounds__(256) void gemm1_scatter_kernel(
    const float* __restrict__ Av,
    const unsigned short* __restrict__ WTl,
    const unsigned short* __restrict__ WTr,
    const float* __restrict__ bias,
    unsigned char* __restrict__ Pl,
    unsigned short* __restrict__ Qr, int M,
    const unsigned* __restrict__ bucket,
    const int* __restrict__ bucket_cnt,
    const int* __restrict__ cur, unsigned short* __restrict__ csr_src,
    int nGemmWg, int N) {
    __shared__ __align__(16) int lcur[RANGE_W];
    const int tid = threadIdx.x;

    if ((int)blockIdx.x < nGemmWg) {
        const int wave = tid >> 6;
        const int lane = tid & 63;
        const int lr = lane & 15;
        const int lk = lane >> 4;

        bf16x8 bfr[2][2][4];
        float4 b4[2];
#pragma unroll
        for (int c = 0; c < 2; ++c) {
            int ct = wave * 2 + c;
            const unsigned short* Bl = WTl + (size_t)(ct * 16 + lr) * 128 + lk * 8;
            const unsigned short* Br = WTr + (size_t)(ct * 16 + lr) * 128 + lk * 8;
#pragma unroll
            for (int s = 0; s < 4; ++s) {
                bfr[c][0][s] = *(const bf16x8*)(Bl + s * 32);
                bfr[c][1][s] = *(const bf16x8*)(Br + s * 32);
            }
            b4[c] = *(const float4*)(bias + ct * 16 + lk * 4);
        }

#pragma unroll
        for (int rt = 0; rt < 4; ++rt) {
            const int m0 = blockIdx.x * 64 + rt * 16;
            int arow = m0 + lr;
            if (arow >= M) arow = M - 1;
            const bool rowok = (m0 + lr) < M;

            bf16x8 xf[4];
            const float* Ab = Av + (size_t)arow * 128 + lk * 8;
#pragma unroll
            for (int s = 0; s < 4; ++s) {
                float4 v0 = *(const float4*)(Ab + s * 32);
                float4 v1 = *(const float4*)(Ab + s * 32 + 4);
                unsigned short t[8] = {f2bf(v0.x), f2bf(v0.y), f2bf(v0.z), f2bf(v0.w),
                                       f2bf(v1.x), f2bf(v1.y), f2bf(v1.z), f2bf(v1.w)};
                xf[s] = *(const bf16x8*)t;
            }

#pragma unroll
            for (int c = 0; c < 2; ++c) {
                int ct = wave * 2 + c;
                f32x4 accL = {0.f, 0.f, 0.f, 0.f};
                f32x4 accR = {0.f, 0.f, 0.f, 0.f};
#pragma unroll
                for (int s = 0; s < 4; ++s) {
                    accL = __builtin_amdgcn_mfma_f32_16x16x32_bf16(bfr[c][0][s], xf[s], accL, 0, 0, 0);
                    accR = __builtin_amdgcn_mfma_f32_16x16x32_bf16(bfr[c][1][s], xf[s], accR, 0, 0, 0);
                }
                if (rowok) {
                    unsigned pk = pk4_fp8(accL[0], accL[1], accL[2], accL[3]);
                    ushort4 oR;
                    oR.x = f2bf(accR[0] + b4[c].x); oR.y = f2bf(accR[1] + b4[c].y);
                    oR.z = f2bf(accR[2] + b4[c].z); oR.w = f2bf(accR[3] + b4[c].w);
                    size_t base = (size_t)(m0 + lr) * 128 + ct * 16 + lk * 4;
                    *(unsigned*)(Pl + base) = pk;
                    *(ushort4*)(Qr + base) = oR;
                }
            }
        }
        return;
    }

    // ---- scatter path ----
    const int b = blockIdx.x - nGemmWg;
    const int r = b & (NRANGE - 1);
    const int j = b >> 3;
    const int lo = r * RANGE_W;
    const int w = min(N - lo, RANGE_W);
    const int* gb = cur + ((size_t)r * NSTRIPE + j) * RANGE_W;
    {
        int w4 = w & ~3;
        for (int i = tid * 4; i < w4; i += 1024)
            *(int4*)(&lcur[i]) = *(const int4*)(gb + i);
        for (int i = w4 + tid; i < w; i += 256) lcur[i] = gb[i];
    }
    __syncthreads();
    const int cnt = bucket_cnt[r * NSTRIPE + j];
    const unsigned* gbk = bucket + (size_t)(r * NSTRIPE + j) * BUCKET_CAP;
    for (int i = tid; i < cnt; i += 256) {
        unsigned pk = gbk[i];
        int node = (int)(pk & 0xffffu) - lo;
        int pos = atomicAdd(&lcur[node], 1);
        csr_src[pos] = (unsigned short)(pk >> 16);
    }
}

// ---------------- D5: agg1 + fused GEMM-2 (g fp8, r bf16) ----------------

__global__ __launch_bounds__(256) void agg1_gemm2_kernel(
    const unsigned char* __restrict__ p,
    const unsigned short* __restrict__ q,
    const int* __restrict__ row_start,
    const unsigned short* __restrict__ csr_src,
    const unsigned short* __restrict__ wt2l,
    const unsigned short* __restrict__ wt2r,
    const float* __restrict__ b2,
    unsigned char* __restrict__ g,
    unsigned short* __restrict__ rbuf, int N) {
    __shared__ unsigned short hsh[16][136];
    int tid = threadIdx.x;
    int nl = tid >> 4;
    int lane = tid & 15;
    int n = blockIdx.x * 16 + nl;
    int na = min(n, N - 1);
    int s0 = row_start[na], s1 = row_start[na + 1];
    float acc[8] = {};
    const unsigned char* pc = p + lane * 8;
    int e = s0;
    for (; e + 7 < s1; e += 8) {
        uint2 v0 = *(const uint2*)(pc + (size_t)csr_src[e]     * 128);
        uint2 v1 = *(const uint2*)(pc + (size_t)csr_src[e + 1] * 128);
        uint2 v2 = *(const uint2*)(pc + (size_t)csr_src[e + 2] * 128);
        uint2 v3 = *(const uint2*)(pc + (size_t)csr_src[e + 3] * 128);
        uint2 v4 = *(const uint2*)(pc + (size_t)csr_src[e + 4] * 128);
        uint2 v5 = *(const uint2*)(pc + (size_t)csr_src[e + 5] * 128);
        uint2 v6 = *(const uint2*)(pc + (size_t)csr_src[e + 6] * 128);
        uint2 v7 = *(const uint2*)(pc + (size_t)csr_src[e + 7] * 128);
        acc8_fp8(acc, v0); acc8_fp8(acc, v1); acc8_fp8(acc, v2); acc8_fp8(acc, v3);
        acc8_fp8(acc, v4); acc8_fp8(acc, v5); acc8_fp8(acc, v6); acc8_fp8(acc, v7);
    }
    for (; e + 3 < s1; e += 4) {
        uint2 v0 = *(const uint2*)(pc + (size_t)csr_src[e]     * 128);
        uint2 v1 = *(const uint2*)(pc + (size_t)csr_src[e + 1] * 128);
        uint2 v2 = *(const uint2*)(pc + (size_t)csr_src[e + 2] * 128);
        uint2 v3 = *(const uint2*)(pc + (size_t)csr_src[e + 3] * 128);
        acc8_fp8(acc, v0); acc8_fp8(acc, v1); acc8_fp8(acc, v2); acc8_fp8(acc, v3);
    }
    for (; e < s1; ++e) {
        uint2 v0 = *(const uint2*)(pc + (size_t)csr_src[e] * 128);
        acc8_fp8(acc, v0);
    }
    float inv = 1.0f / (float)max(s1 - s0, 1);
    uint4 qv = *(const uint4*)(q + (size_t)na * 128 + lane * 8);
    float hv[8];
    hv[0] = fmaxf(fmaf(acc[0], inv, bf_lo(qv.x)), 0.f);
    hv[1] = fmaxf(fmaf(acc[1], inv, bf_hi(qv.x)), 0.f);
    hv[2] = fmaxf(fmaf(acc[2], inv, bf_lo(qv.y)), 0.f);
    hv[3] = fmaxf(fmaf(acc[3], inv, bf_hi(qv.y)), 0.f);
    hv[4] = fmaxf(fmaf(acc[4], inv, bf_lo(qv.z)), 0.f);
    hv[5] = fmaxf(fmaf(acc[5], inv, bf_hi(qv.z)), 0.f);
    hv[6] = fmaxf(fmaf(acc[6], inv, bf_lo(qv.w)), 0.f);
    hv[7] = fmaxf(fmaf(acc[7], inv, bf_hi(qv.w)), 0.f);
    uint4 o;
    o.x = packbf(hv[0], hv[1]); o.y = packbf(hv[2], hv[3]);
    o.z = packbf(hv[4], hv[5]); o.w = packbf(hv[6], hv[7]);
    *(uint4*)(&hsh[nl][lane * 8]) = o;
    __syncthreads();

    const int wave = tid >> 6;
    const int wl = tid & 63;
    const int lr = wl & 15;
    const int lk = wl >> 4;
    const int gn = blockIdx.x * 16 + lr;
    const bool rowok = gn < N;
    const int ct = wave;
    f32x4 aL = {0.f, 0.f, 0.f, 0.f};
    f32x4 aR = {0.f, 0.f, 0.f, 0.f};
#pragma unroll
    for (int s = 0; s < 4; ++s) {
        bf16x8 hvv = *(const bf16x8*)(&hsh[lr][lk * 8 + s * 32]);
        bf16x8 bl = *(const bf16x8*)(wt2l + (size_t)(ct * 16 + lr) * 128 + lk * 8 + s * 32);
        bf16x8 br = *(const bf16x8*)(wt2r + (size_t)(ct * 16 + lr) * 128 + lk * 8 + s * 32);
        aL = __builtin_amdgcn_mfma_f32_16x16x32_bf16(bl, hvv, aL, 0, 0, 0);
        aR = __builtin_amdgcn_mfma_f32_16x16x32_bf16(br, hvv, aR, 0, 0, 0);
    }
    if (rowok) {
        float4 b4 = *(const float4*)(b2 + ct * 16 + lk * 4);
        unsigned pg = pk4_fp8(aL[0], aL[1], aL[2], aL[3]);
        ushort4 oR;
        oR.x = f2bf(aR[0] + b4.x); oR.y = f2bf(aR[1] + b4.y);
        oR.z = f2bf(aR[2] + b4.z); oR.w = f2bf(aR[3] + b4.w);
        size_t base = (size_t)gn * 64 + ct * 16 + lk * 4;
        *(unsigned*)(g + base) = pg;
        *(ushort4*)(rbuf + base) = oR;
    }
}

// ---------------- D6: agg2 (fp8 g gather) ----------------

__global__ __launch_bounds__(256) void agg2_kernel(const unsigned char* __restrict__ g,
                                                   const unsigned short* __restrict__ r,
                                                   const int* __restrict__ row_start,
                                                   const unsigned short* __restrict__ csr_src,
                                                   float* __restrict__ out, int N) {
    int tid = threadIdx.x;
    int n = blockIdx.x * 16 + (tid >> 4);
    int lane = tid & 15;
    if (n >= N) return;
    int s0 = row_start[n], s1 = row_start[n + 1];
    float acc[4] = {};
    const unsigned char* gc = g + lane * 4;
    int e = s0;
    for (; e + 7 < s1; e += 8) {
        unsigned v0 = *(const unsigned*)(gc + (size_t)csr_src[e]     * 64);
        unsigned v1 = *(const unsigned*)(gc + (size_t)csr_src[e + 1] * 64);
        unsigned v2 = *(const unsigned*)(gc + (size_t)csr_src[e + 2] * 64);
        unsigned v3 = *(const unsigned*)(gc + (size_t)csr_src[e + 3] * 64);
        unsigned v4 = *(const unsigned*)(gc + (size_t)csr_src[e + 4] * 64);
        unsigned v5 = *(const unsigned*)(gc + (size_t)csr_src[e + 5] * 64);
        unsigned v6 = *(const unsigned*)(gc + (size_t)csr_src[e + 6] * 64);
        unsigned v7 = *(const unsigned*)(gc + (size_t)csr_src[e + 7] * 64);
        acc4_fp8(acc, v0); acc4_fp8(acc, v1); acc4_fp8(acc, v2); acc4_fp8(acc, v3);
        acc4_fp8(acc, v4); acc4_fp8(acc, v5); acc4_fp8(acc, v6); acc4_fp8(acc, v7);
    }
    for (; e + 3 < s1; e += 4) {
        unsigned v0 = *(const unsigned*)(gc + (size_t)csr_src[e]     * 64);
        unsigned v1 = *(const unsigned*)(gc + (size_t)csr_src[e + 1] * 64);
        unsigned v2 = *(const unsigned*)(gc + (size_t)csr_src[e + 2] * 64);
        unsigned v3 = *(const unsigned*)(gc + (size_t)csr_src[e + 3] * 64);
        acc4_fp8(acc, v0); acc4_fp8(acc, v1); acc4_fp8(acc, v2); acc4_fp8(acc, v3);
    }
    for (; e < s1; ++e) {
        unsigned v0 = *(const unsigned*)(gc + (size_t)csr_src[e] * 64);
        acc4_fp8(acc, v0);
    }
    float inv = 1.0f / (float)max(s1 - s0, 1);
    uint2 rv = *(const uint2*)(r + (size_t)n * 64 + lane * 4);
    float4 o;
    o.x = fmaf(acc[0], inv, bf_lo(rv.x));
    o.y = fmaf(acc[1], inv, bf_hi(rv.x));
    o.z = fmaf(acc[2], inv, bf_lo(rv.y));
    o.w = fmaf(acc[3], inv, bf_hi(rv.y));
    *(float4*)(out + (size_t)n * 64 + lane * 4) = o;
}

// ---------------------------------------------------------------------------

extern "C" void kernel_launch(void* const* d_in, const int* in_sizes, int n_in,
                              void* d_out, int out_size, void* d_ws, size_t ws_size,
                              hipStream_t stream) {
    const float* x    = (const float*)d_in[0];
    const int*   ei   = (const int*)d_in[1];
    const float* W1_l = (const float*)d_in[2];
    const float* b1   = (const float*)d_in[3];
    const float* W1_r = (const float*)d_in[4];
    const float* W2_l = (const float*)d_in[5];
    const float* b2   = (const float*)d_in[6];
    const float* W2_r = (const float*)d_in[7];

    const int N = in_sizes[0] / 128;   // 50000
    const int E = in_sizes[1] / 2;     // 800000
    const int* e_src = ei;
    const int* e_dst = ei + E;

    // ---- workspace layout ----
    char* ws = (char*)d_ws;
    auto align256 = [](size_t v) { return (v + 255) & ~(size_t)255; };
    size_t off = 0;
    int* row_start = (int*)(ws + off); off += align256((size_t)(N + 1) * 4);
    int* bsum      = (int*)(ws + off); off += align256(1024);
    int* hist      = (int*)(ws + off); off += align256((size_t)NRANGE * NSTRIPE * PACKED_W * 4);
    int* cur       = (int*)(ws + off); off += align256((size_t)NRANGE * NSTRIPE * RANGE_W * 4);
    unsigned* bucket = (unsigned*)(ws + off); off += align256((size_t)NHIST * BUCKET_CAP * 4);
    int* bucket_cnt  = (int*)(ws + off); off += align256((size_t)NHIST * 4);
    unsigned short* csr_src = (unsigned short*)(ws + off); off += align256((size_t)E * 2);
    unsigned char* p_f8   = (unsigned char*)(ws + off);  off += align256((size_t)N * 128);
    unsigned short* qr_bf = (unsigned short*)(ws + off); off += align256((size_t)N * 128 * 2);
    unsigned char* g_f8   = (unsigned char*)(ws + off);  off += align256((size_t)N * 64);
    unsigned short* r_bf  = (unsigned short*)(ws + off); off += align256((size_t)N * 64 * 2);
    unsigned short* wt1l  = (unsigned short*)(ws + off); off += align256(128 * 128 * 2);
    unsigned short* wt1r  = (unsigned short*)(ws + off); off += align256(128 * 128 * 2);
    unsigned short* wt2l  = (unsigned short*)(ws + off); off += align256(128 * 64 * 2);
    unsigned short* wt2r  = (unsigned short*)(ws + off); off += align256(128 * 64 * 2);
    float* out = (float*)d_out;

    const int nb = (N + 255) / 256;
    const int nGemm1Wg = (N + 63) / 64;                   // 782 (64 rows/block)
    const int nWtWg = (16384 + 8192 + 511) / 512;         // 48

    // ---- D1: histogram + range-buckets + weight prep (hist first) ----
    hist_wt_kernel<<<NHIST + nWtWg, 512, 0, stream>>>(
        e_src, e_dst, hist, bucket, bucket_cnt, E, N,
        W1_l, W1_r, W2_l, W2_r, wt1l, wt1r, wt2l, wt2r);
    // ---- D2/D3: CSR scan (no global atomics) ----
    scan16_kernel<<<nb, 256, 0, stream>>>(hist, row_start, bsum, N);
    add_off_base_kernel<<<nb, 256, 0, stream>>>(row_start, bsum, hist, cur, N, E);
    // ---- D4: GEMM-1 (reg weights) + scatter, fused (gemm first) ----
    gemm1_scatter_kernel<<<nGemm1Wg + NHIST, 256, 0, stream>>>(
        x, wt1l, wt1r, b1, p_f8, qr_bf, N,
        bucket, bucket_cnt, cur, csr_src, nGemm1Wg, N);
    // ---- D5: agg1 (fp8 gather) + fused GEMM-2 (g fp8, r bf16) ----
    agg1_gemm2_kernel<<<(N + 15) / 16, 256, 0, stream>>>(
        p_f8, qr_bf, row_start, csr_src, wt2l, wt2r, b2, g_f8, r_bf, N);
    // ---- D6: agg2 (fp8 g) ----
    agg2_kernel<<<(N + 15) / 16, 256, 0, stream>>>(g_f8, r_bf, row_start,
                                                   csr_src, out, N);
}